// Round 5
// baseline (178.330 us; speedup 1.0000x reference)
//
#include <hip/hip_runtime.h>
#include <cmath>

// CriticSNN forward: BATCH=65536, STATE_DIM=6, HIDDEN=128, NUM_STEPS=8, OUT=1
// One wave per batch element-PAIR; lane l owns neurons l and l+64 of each.
// Spikes are binary -> ballots; matmuls are masked column sums.
//
// v5: occupancy unlock. v1/v3/v4 showed constant VALU-busy TIME (~31 us)
// across big instruction-count changes -> latency-bound at 4 waves/SIMD
// (128 KiB LDS table allows only 1 block/CU). Fix: pack the gather table
// into GLOBAL memory in the same j-major/lane-minor layout (prep kernel,
// workspace). Gathers stay perfectly coalesced (1 KiB per uniform-j load),
// table is L2-resident, LDS -> 0, occupancy cap doubles to 8 waves/SIMD.
// v2's global failure was per-lane ROW layout (64 lines/load), not global
// per se. Fallback to the proven v4 LDS kernel if workspace is too small.

typedef float f32x2 __attribute__((ext_vector_type(2)));
typedef float f32x4 __attribute__((ext_vector_type(4)));

constexpr int BATCH = 65536;
constexpr int HID   = 128;
constexpr int SDIM  = 6;
constexpr int NSTEP = 8;

// ---------------- prep: pack {rec1_a, rec1_b, fc2_a, fc2_b} ----------------
// P[(j<<6)|l] = {w_rec1[l][j], w_rec1[l+64][j], w_fc2[l][j], w_fc2[l+64][j]}
__global__ __launch_bounds__(256) void pack_weights(
    const float* __restrict__ w_rec1,
    const float* __restrict__ w_fc2,
    f32x4* __restrict__ P)
{
    const int g = blockIdx.x * 256 + threadIdx.x;  // 0..8191
    const int j = g & 127;                         // consecutive g -> coalesced reads
    const int l = g >> 7;                          // 0..63
    f32x4 w;
    w.x = w_rec1[l * HID + j];
    w.y = w_rec1[(l + 64) * HID + j];
    w.z = w_fc2 [l * HID + j];
    w.w = w_fc2 [(l + 64) * HID + j];
    P[(j << 6) | l] = w;
}

// ---------------- main kernel: zero LDS, packed global gathers -------------
constexpr int BLOCK_G = 512;                          // 8 waves/block
constexpr int GRID_G  = 1024;                         // 4 blocks/CU
constexpr int WAVES_G = GRID_G * (BLOCK_G / 64);      // 8192
constexpr int EPW_G   = BATCH / WAVES_G;              // 8
constexpr int PAIRS_G = EPW_G / 2;                    // 4

__global__ __launch_bounds__(BLOCK_G, 8) void snn_fwd_g(
    const float* __restrict__ state,
    const float* __restrict__ w_fc1,
    const f32x4* __restrict__ P,
    const float* __restrict__ w_rec2,
    const float* __restrict__ w_mean,
    const float* __restrict__ w_std,
    const float* __restrict__ p_alpha1, const float* __restrict__ p_beta1,
    const float* __restrict__ p_thr1,
    const float* __restrict__ p_alpha2, const float* __restrict__ p_beta2,
    const float* __restrict__ p_thr2,
    float* __restrict__ out)
{
    const int tid   = threadIdx.x;
    const int lane  = tid & 63;
    const int gwave = blockIdx.x * (BLOCK_G / 64) + (tid >> 6);

    // small weights -> registers
    f32x2 w1[SDIM];
    #pragma unroll
    for (int k = 0; k < SDIM; ++k) {
        w1[k].x = w_fc1[lane * SDIM + k];
        w1[k].y = w_fc1[(lane + 64) * SDIM + k];
    }
    const float wm_a = w_mean[lane], wm_b = w_mean[lane + 64];
    const float ws_a = w_std [lane], ws_b = w_std [lane + 64];

    const float a1 = fminf(fmaxf(p_alpha1[0], 0.f), 1.f);
    const float b1 = fminf(fmaxf(p_beta1 [0], 0.f), 1.f);
    const float a2 = fminf(fmaxf(p_alpha2[0], 0.f), 1.f);
    const float b2 = fminf(fmaxf(p_beta2 [0], 0.f), 1.f);
    const float t1 = p_thr1[0];
    const float t2 = p_thr2[0];
    const f32x2 a1v = {a1, a1}, b1v = {b1, b1}, a2v = {a2, a2}, b2v = {b2, b2};

    const float* __restrict__ rec2_a = w_rec2 + lane * HID;
    const float* __restrict__ rec2_b = w_rec2 + (lane + 64) * HID;

    const f32x4* __restrict__ baseLo = P;               // j in 0..63
    const f32x4* __restrict__ baseHi = P + (64 << 6);   // j in 64..127

    // fused gather over one spike mask: rec1 (next step) into r, fc2 (this
    // step) into f. One coalesced global_load_dwordx4 per set bit (uniform j,
    // lane-consecutive addresses). Hand-rotated: next load issues before the
    // current accumulate.
    auto walk2 = [&](unsigned long long m, const f32x4* __restrict__ base,
                     f32x2& f, f32x2& r) {
        if (!m) return;
        int j = __builtin_ctzll(m); m &= m - 1;
        f32x4 w = base[(j << 6) | lane];
        while (m) {
            const int j2 = __builtin_ctzll(m); m &= m - 1;
            const f32x4 w2 = base[(j2 << 6) | lane];
            r += __builtin_shufflevector(w, w, 0, 1);
            f += __builtin_shufflevector(w, w, 2, 3);
            w = w2;
        }
        r += __builtin_shufflevector(w, w, 0, 1);
        f += __builtin_shufflevector(w, w, 2, 3);
    };
    auto walkg = [&](unsigned long long m, int jbase, f32x2& f) {
        while (m) {
            const int j = __builtin_ctzll(m) + jbase; m &= m - 1;
            f.x += rec2_a[j];
            f.y += rec2_b[j];
        }
    };

    // preload state for pair 0 (wave-uniform -> scalar loads)
    float sx[SDIM], sy[SDIM];
    #pragma unroll
    for (int k = 0; k < SDIM; ++k) {
        sx[k] = state[(gwave) * SDIM + k];
        sy[k] = state[(gwave + WAVES_G) * SDIM + k];
    }

    for (int e = 0; e < PAIRS_G; ++e) {
        const int bx = gwave + WAVES_G * (2 * e);
        const int by = gwave + WAVES_G * (2 * e + 1);

        f32x2 curx = {0.f, 0.f}, cury = {0.f, 0.f};
        #pragma unroll
        for (int k = 0; k < SDIM; ++k) {
            const f32x2 sxv = {sx[k], sx[k]};
            const f32x2 syv = {sy[k], sy[k]};
            curx = __builtin_elementwise_fma(sxv, w1[k], curx);
            cury = __builtin_elementwise_fma(syv, w1[k], cury);
        }

        float sxn[SDIM], syn2p[SDIM];
        if (e + 1 < PAIRS_G) {
            const int bxn = gwave + WAVES_G * (2 * e + 2);
            const int byn = gwave + WAVES_G * (2 * e + 3);
            #pragma unroll
            for (int k = 0; k < SDIM; ++k) {
                sxn[k]   = state[bxn * SDIM + k];
                syn2p[k] = state[byn * SDIM + k];
            }
        }

        f32x2 s1x = {0.f, 0.f}, m1x = {0.f, 0.f}, s2x = {0.f, 0.f}, m2x = {0.f, 0.f};
        f32x2 s1y = {0.f, 0.f}, m1y = {0.f, 0.f}, s2y = {0.f, 0.f}, m2y = {0.f, 0.f};
        bool k1xa = false, k1xb = false, k2xa = false, k2xb = false;
        bool k1ya = false, k1yb = false, k2ya = false, k2yb = false;
        f32x2 cx = {0.f, 0.f}, cy = {0.f, 0.f};
        unsigned long long M2xa = 0ull, M2xb = 0ull, M2ya = 0ull, M2yb = 0ull;
        f32x2 rx = {0.f, 0.f}, ry = {0.f, 0.f};

        #pragma unroll 1
        for (int t = 0; t < NSTEP; ++t) {
            // ----- layer 1 -----
            s1x = __builtin_elementwise_fma(a1v, s1x, curx + rx);
            s1y = __builtin_elementwise_fma(a1v, s1y, cury + ry);
            const f32x2 rst1x = {k1xa ? t1 : 0.f, k1xb ? t1 : 0.f};
            const f32x2 rst1y = {k1ya ? t1 : 0.f, k1yb ? t1 : 0.f};
            m1x = __builtin_elementwise_fma(b1v, m1x, s1x) - rst1x;
            m1y = __builtin_elementwise_fma(b1v, m1y, s1y) - rst1y;
            k1xa = (m1x.x - t1) > 0.f;
            k1xb = (m1x.y - t1) > 0.f;
            k1ya = (m1y.x - t1) > 0.f;
            k1yb = (m1y.y - t1) > 0.f;
            const unsigned long long M1xa = __ballot(k1xa);
            const unsigned long long M1xb = __ballot(k1xb);
            const unsigned long long M1ya = __ballot(k1ya);
            const unsigned long long M1yb = __ballot(k1yb);

            // ----- fused gathers: fc2 (this step) + rec1 (next step) -----
            f32x2 fx = {0.f, 0.f}, fy = {0.f, 0.f};
            rx = (f32x2){0.f, 0.f}; ry = (f32x2){0.f, 0.f};
            walk2(M1xa, baseLo, fx, rx);
            walk2(M1ya, baseLo, fy, ry);
            walk2(M1xb, baseHi, fx, rx);
            walk2(M1yb, baseHi, fy, ry);

            if ((M2xa | M2xb | M2ya | M2yb) != 0ull) {
                walkg(M2xa, 0,  fx);
                walkg(M2xb, 64, fx);
                walkg(M2ya, 0,  fy);
                walkg(M2yb, 64, fy);
            }

            // ----- layer 2 -----
            s2x = __builtin_elementwise_fma(a2v, s2x, fx);
            s2y = __builtin_elementwise_fma(a2v, s2y, fy);
            const f32x2 rst2x = {k2xa ? t2 : 0.f, k2xb ? t2 : 0.f};
            const f32x2 rst2y = {k2ya ? t2 : 0.f, k2yb ? t2 : 0.f};
            m2x = __builtin_elementwise_fma(b2v, m2x, s2x) - rst2x;
            m2y = __builtin_elementwise_fma(b2v, m2y, s2y) - rst2y;
            k2xa = (m2x.x - t2) > 0.f;
            k2xb = (m2x.y - t2) > 0.f;
            k2ya = (m2y.x - t2) > 0.f;
            k2yb = (m2y.y - t2) > 0.f;
            M2xa = __ballot(k2xa);
            M2xb = __ballot(k2xb);
            M2ya = __ballot(k2ya);
            M2yb = __ballot(k2yb);
            const f32x2 onex = {k2xa ? 1.f : 0.f, k2xb ? 1.f : 0.f};
            const f32x2 oney = {k2ya ? 1.f : 0.f, k2yb ? 1.f : 0.f};
            cx += onex;
            cy += oney;
        }

        // ----- head -----
        const float axa = cx.x * (1.f / (float)NSTEP);
        const float axb = cx.y * (1.f / (float)NSTEP);
        const float aya = cy.x * (1.f / (float)NSTEP);
        const float ayb = cy.y * (1.f / (float)NSTEP);
        float dmx = axa * wm_a + axb * wm_b;
        float dsx = axa * ws_a + axb * ws_b;
        float dmy = aya * wm_a + ayb * wm_b;
        float dsy = aya * ws_a + ayb * ws_b;
        #pragma unroll
        for (int off = 32; off > 0; off >>= 1) {
            dmx += __shfl_xor(dmx, off, 64);
            dsx += __shfl_xor(dsx, off, 64);
            dmy += __shfl_xor(dmy, off, 64);
            dsy += __shfl_xor(dsy, off, 64);
        }
        if (lane == 0) {
            out[bx] = tanhf(dmx);
            out[by] = tanhf(dmy);
            const float sgx = 1.f / (1.f + expf(-(dsx + 2.f)));
            const float sgy = 1.f / (1.f + expf(-(dsy + 2.f)));
            out[BATCH + bx] = 1.9f * sgx + 0.1f;
            out[BATCH + by] = 1.9f * sgy + 0.1f;
        }

        if (e + 1 < PAIRS_G) {
            #pragma unroll
            for (int k = 0; k < SDIM; ++k) { sx[k] = sxn[k]; sy[k] = syn2p[k]; }
        }
    }
}

// ---------------- fallback: v4 LDS kernel (workspace too small) ------------
constexpr int BLOCK_L = 1024;
constexpr int GRID_L  = 256;
constexpr int WAVES_L = GRID_L * (BLOCK_L / 64);
constexpr int EPW_L   = BATCH / WAVES_L;
constexpr int PAIRS_L = EPW_L / 2;

__global__ __launch_bounds__(BLOCK_L) void snn_fwd_lds(
    const float* __restrict__ state,
    const float* __restrict__ w_fc1,
    const float* __restrict__ w_rec1,
    const float* __restrict__ w_fc2,
    const float* __restrict__ w_rec2,
    const float* __restrict__ w_mean,
    const float* __restrict__ w_std,
    const float* __restrict__ p_alpha1, const float* __restrict__ p_beta1,
    const float* __restrict__ p_thr1,
    const float* __restrict__ p_alpha2, const float* __restrict__ p_beta2,
    const float* __restrict__ p_thr2,
    float* __restrict__ out)
{
    __shared__ f32x4 ldw[HID * 64];   // 128 KiB
    const int tid = threadIdx.x;

    for (int v = tid; v < HID * 64; v += BLOCK_L) {
        const int l = v >> 7;
        const int j = v & 127;
        const int pos = (j << 6) | (l ^ (j & 63));
        f32x4 w;
        w.x = w_rec1[l * HID + j];
        w.y = w_rec1[(l + 64) * HID + j];
        w.z = w_fc2 [l * HID + j];
        w.w = w_fc2 [(l + 64) * HID + j];
        ldw[pos] = w;
    }

    const int lane  = tid & 63;
    const int gwave = blockIdx.x * (BLOCK_L / 64) + (tid >> 6);

    f32x2 w1[SDIM];
    #pragma unroll
    for (int k = 0; k < SDIM; ++k) {
        w1[k].x = w_fc1[lane * SDIM + k];
        w1[k].y = w_fc1[(lane + 64) * SDIM + k];
    }
    const float wm_a = w_mean[lane], wm_b = w_mean[lane + 64];
    const float ws_a = w_std [lane], ws_b = w_std [lane + 64];

    const float a1 = fminf(fmaxf(p_alpha1[0], 0.f), 1.f);
    const float b1 = fminf(fmaxf(p_beta1 [0], 0.f), 1.f);
    const float a2 = fminf(fmaxf(p_alpha2[0], 0.f), 1.f);
    const float b2 = fminf(fmaxf(p_beta2 [0], 0.f), 1.f);
    const float t1 = p_thr1[0];
    const float t2 = p_thr2[0];
    const f32x2 a1v = {a1, a1}, b1v = {b1, b1}, a2v = {a2, a2}, b2v = {b2, b2};

    const float* __restrict__ rec2_a = w_rec2 + lane * HID;
    const float* __restrict__ rec2_b = w_rec2 + (lane + 64) * HID;

    __syncthreads();

    auto walk2 = [&](unsigned long long m, const f32x4* __restrict__ base,
                     f32x2& f, f32x2& r) {
        if (!m) return;
        int j = __builtin_ctzll(m); m &= m - 1;
        f32x4 w = base[(j << 6) | (lane ^ j)];
        while (m) {
            const int j2 = __builtin_ctzll(m); m &= m - 1;
            const f32x4 w2 = base[(j2 << 6) | (lane ^ j2)];
            r += __builtin_shufflevector(w, w, 0, 1);
            f += __builtin_shufflevector(w, w, 2, 3);
            w = w2;
        }
        r += __builtin_shufflevector(w, w, 0, 1);
        f += __builtin_shufflevector(w, w, 2, 3);
    };
    auto walkg = [&](unsigned long long m, int jbase, f32x2& f) {
        while (m) {
            const int j = __builtin_ctzll(m) + jbase; m &= m - 1;
            f.x += rec2_a[j];
            f.y += rec2_b[j];
        }
    };

    const f32x4* __restrict__ baseLo = ldw;
    const f32x4* __restrict__ baseHi = ldw + (64 << 6);

    float sx[SDIM], sy[SDIM];
    #pragma unroll
    for (int k = 0; k < SDIM; ++k) {
        sx[k] = state[(gwave) * SDIM + k];
        sy[k] = state[(gwave + WAVES_L) * SDIM + k];
    }

    for (int e = 0; e < PAIRS_L; ++e) {
        const int bx = gwave + WAVES_L * (2 * e);
        const int by = gwave + WAVES_L * (2 * e + 1);

        f32x2 curx = {0.f, 0.f}, cury = {0.f, 0.f};
        #pragma unroll
        for (int k = 0; k < SDIM; ++k) {
            const f32x2 sxv = {sx[k], sx[k]};
            const f32x2 syv = {sy[k], sy[k]};
            curx = __builtin_elementwise_fma(sxv, w1[k], curx);
            cury = __builtin_elementwise_fma(syv, w1[k], cury);
        }

        float sxn[SDIM], syn2p[SDIM];
        if (e + 1 < PAIRS_L) {
            const int bxn = gwave + WAVES_L * (2 * e + 2);
            const int byn = gwave + WAVES_L * (2 * e + 3);
            #pragma unroll
            for (int k = 0; k < SDIM; ++k) {
                sxn[k]   = state[bxn * SDIM + k];
                syn2p[k] = state[byn * SDIM + k];
            }
        }

        f32x2 s1x = {0.f, 0.f}, m1x = {0.f, 0.f}, s2x = {0.f, 0.f}, m2x = {0.f, 0.f};
        f32x2 s1y = {0.f, 0.f}, m1y = {0.f, 0.f}, s2y = {0.f, 0.f}, m2y = {0.f, 0.f};
        bool k1xa = false, k1xb = false, k2xa = false, k2xb = false;
        bool k1ya = false, k1yb = false, k2ya = false, k2yb = false;
        f32x2 cx = {0.f, 0.f}, cy = {0.f, 0.f};
        unsigned long long M2xa = 0ull, M2xb = 0ull, M2ya = 0ull, M2yb = 0ull;
        f32x2 rx = {0.f, 0.f}, ry = {0.f, 0.f};

        #pragma unroll 1
        for (int t = 0; t < NSTEP; ++t) {
            s1x = __builtin_elementwise_fma(a1v, s1x, curx + rx);
            s1y = __builtin_elementwise_fma(a1v, s1y, cury + ry);
            const f32x2 rst1x = {k1xa ? t1 : 0.f, k1xb ? t1 : 0.f};
            const f32x2 rst1y = {k1ya ? t1 : 0.f, k1yb ? t1 : 0.f};
            m1x = __builtin_elementwise_fma(b1v, m1x, s1x) - rst1x;
            m1y = __builtin_elementwise_fma(b1v, m1y, s1y) - rst1y;
            k1xa = (m1x.x - t1) > 0.f;
            k1xb = (m1x.y - t1) > 0.f;
            k1ya = (m1y.x - t1) > 0.f;
            k1yb = (m1y.y - t1) > 0.f;
            const unsigned long long M1xa = __ballot(k1xa);
            const unsigned long long M1xb = __ballot(k1xb);
            const unsigned long long M1ya = __ballot(k1ya);
            const unsigned long long M1yb = __ballot(k1yb);

            f32x2 fx = {0.f, 0.f}, fy = {0.f, 0.f};
            rx = (f32x2){0.f, 0.f}; ry = (f32x2){0.f, 0.f};
            walk2(M1xa, baseLo, fx, rx);
            walk2(M1ya, baseLo, fy, ry);
            walk2(M1xb, baseHi, fx, rx);
            walk2(M1yb, baseHi, fy, ry);

            if ((M2xa | M2xb | M2ya | M2yb) != 0ull) {
                walkg(M2xa, 0,  fx);
                walkg(M2xb, 64, fx);
                walkg(M2ya, 0,  fy);
                walkg(M2yb, 64, fy);
            }

            s2x = __builtin_elementwise_fma(a2v, s2x, fx);
            s2y = __builtin_elementwise_fma(a2v, s2y, fy);
            const f32x2 rst2x = {k2xa ? t2 : 0.f, k2xb ? t2 : 0.f};
            const f32x2 rst2y = {k2ya ? t2 : 0.f, k2yb ? t2 : 0.f};
            m2x = __builtin_elementwise_fma(b2v, m2x, s2x) - rst2x;
            m2y = __builtin_elementwise_fma(b2v, m2y, s2y) - rst2y;
            k2xa = (m2x.x - t2) > 0.f;
            k2xb = (m2x.y - t2) > 0.f;
            k2ya = (m2y.x - t2) > 0.f;
            k2yb = (m2y.y - t2) > 0.f;
            M2xa = __ballot(k2xa);
            M2xb = __ballot(k2xb);
            M2ya = __ballot(k2ya);
            M2yb = __ballot(k2yb);
            const f32x2 onex = {k2xa ? 1.f : 0.f, k2xb ? 1.f : 0.f};
            const f32x2 oney = {k2ya ? 1.f : 0.f, k2yb ? 1.f : 0.f};
            cx += onex;
            cy += oney;
        }

        const float axa = cx.x * (1.f / (float)NSTEP);
        const float axb = cx.y * (1.f / (float)NSTEP);
        const float aya = cy.x * (1.f / (float)NSTEP);
        const float ayb = cy.y * (1.f / (float)NSTEP);
        float dmx = axa * wm_a + axb * wm_b;
        float dsx = axa * ws_a + axb * ws_b;
        float dmy = aya * wm_a + ayb * wm_b;
        float dsy = aya * ws_a + ayb * ws_b;
        #pragma unroll
        for (int off = 32; off > 0; off >>= 1) {
            dmx += __shfl_xor(dmx, off, 64);
            dsx += __shfl_xor(dsx, off, 64);
            dmy += __shfl_xor(dmy, off, 64);
            dsy += __shfl_xor(dsy, off, 64);
        }
        if (lane == 0) {
            out[bx] = tanhf(dmx);
            out[by] = tanhf(dmy);
            const float sgx = 1.f / (1.f + expf(-(dsx + 2.f)));
            const float sgy = 1.f / (1.f + expf(-(dsy + 2.f)));
            out[BATCH + bx] = 1.9f * sgx + 0.1f;
            out[BATCH + by] = 1.9f * sgy + 0.1f;
        }

        if (e + 1 < PAIRS_L) {
            #pragma unroll
            for (int k = 0; k < SDIM; ++k) { sx[k] = sxn[k]; sy[k] = syn2p[k]; }
        }
    }
}

extern "C" void kernel_launch(void* const* d_in, const int* in_sizes, int n_in,
                              void* d_out, int out_size, void* d_ws, size_t ws_size,
                              hipStream_t stream) {
    (void)in_sizes; (void)n_in; (void)out_size;
    if (d_ws != nullptr && ws_size >= (size_t)(HID * 64 * sizeof(f32x4))) {
        f32x4* P = (f32x4*)d_ws;
        pack_weights<<<32, 256, 0, stream>>>(
            (const float*)d_in[2], (const float*)d_in[3], P);
        snn_fwd_g<<<GRID_G, BLOCK_G, 0, stream>>>(
            (const float*)d_in[0],  // state
            (const float*)d_in[1],  // w_fc1
            P,
            (const float*)d_in[4],  // w_rec2
            (const float*)d_in[5],  // w_mean
            (const float*)d_in[6],  // w_std
            (const float*)d_in[7], (const float*)d_in[8], (const float*)d_in[9],
            (const float*)d_in[10], (const float*)d_in[11], (const float*)d_in[12],
            (float*)d_out);
    } else {
        snn_fwd_lds<<<GRID_L, BLOCK_L, 0, stream>>>(
            (const float*)d_in[0], (const float*)d_in[1], (const float*)d_in[2],
            (const float*)d_in[3], (const float*)d_in[4], (const float*)d_in[5],
            (const float*)d_in[6],
            (const float*)d_in[7], (const float*)d_in[8], (const float*)d_in[9],
            (const float*)d_in[10], (const float*)d_in[11], (const float*)d_in[12],
            (float*)d_out);
    }
}

// Round 7
// 131.315 us; speedup vs baseline: 1.3580x; 1.3580x over previous
//
#include <hip/hip_runtime.h>
#include <cmath>

// CriticSNN forward: BATCH=65536, STATE_DIM=6, HIDDEN=128, NUM_STEPS=8, OUT=1
// One wave per batch element; lane l owns neurons l and l+64.
// Spikes are binary -> ballots; matmuls are masked column sums.
//
// v6b: split-table occupancy unlock (v6 had a make_float2/ext_vector_type
// compile clash; logic unchanged).
//  - v5 post-mortem: __launch_bounds__ arg2 is min BLOCKS/CU; (512,8) forced
//    a 32-VGPR cap -> 200 MB scratch spill traffic. Fixed.
//  - fc2 (needed immediately after the ballot) stays in LDS: 64 KiB float2
//    -> 2 blocks/CU -> 32 waves/CU (2x the v4 cap).
//  - rec1 (needed only NEXT step: a full layer-2 of slack) comes from a
//    packed global table R[(j<<6)|lane] -- one coalesced 512 B load per set
//    bit, L2-resident. DS bytes/bit halve; L2 absorbs the other half.
//  - one element per wave: state loads and masks are wave-uniform (SGPRs),
//    keeping VGPR <= 64 for the 2-blocks/CU cap.
// Fallback to the proven v4 LDS kernel if workspace < 64 KiB.

typedef float f32x2 __attribute__((ext_vector_type(2)));
typedef float f32x4 __attribute__((ext_vector_type(4)));

constexpr int BATCH = 65536;
constexpr int HID   = 128;
constexpr int SDIM  = 6;
constexpr int NSTEP = 8;

// ---------------- prep: pack rec1 into R[(j<<6)|l] = {rec1[l][j], rec1[l+64][j]}
__global__ __launch_bounds__(256) void pack_rec1(
    const float* __restrict__ w_rec1,
    f32x2* __restrict__ R)
{
    const int g = blockIdx.x * 256 + threadIdx.x;  // 0..8191
    const int l = g & 63;
    const int j = g >> 6;                          // 0..127
    f32x2 w;
    w.x = w_rec1[l * HID + j];
    w.y = w_rec1[(l + 64) * HID + j];
    R[g] = w;                                      // (j<<6)|l == g : coalesced
}

// ---------------- main kernel: fc2 in LDS, rec1 from packed global ---------
constexpr int BLOCK_S = 1024;                         // 16 waves/block
constexpr int GRID_S  = 512;                          // 2 blocks/CU
constexpr int WAVES_S = GRID_S * (BLOCK_S / 64);      // 8192
constexpr int EPW_S   = BATCH / WAVES_S;              // 8

__global__ __launch_bounds__(BLOCK_S, 2) void snn_fwd_split(
    const float* __restrict__ state,
    const float* __restrict__ w_fc1,
    const f32x2* __restrict__ R,        // packed rec1
    const float* __restrict__ w_fc2,
    const float* __restrict__ w_rec2,
    const float* __restrict__ w_mean,
    const float* __restrict__ w_std,
    const float* __restrict__ p_alpha1, const float* __restrict__ p_beta1,
    const float* __restrict__ p_thr1,
    const float* __restrict__ p_alpha2, const float* __restrict__ p_beta2,
    const float* __restrict__ p_thr2,
    float* __restrict__ out)
{
    // fc2 entry (j, l) at index j*64 + (l ^ (j & 63))
    __shared__ f32x2 ld_fc2[HID * 64];   // 64 KiB

    const int tid = threadIdx.x;

    for (int v = tid; v < HID * 64; v += BLOCK_S) {
        const int l = v >> 7;        // 0..63
        const int j = v & 127;       // consecutive lanes -> consecutive j (coalesced)
        const int pos = (j << 6) | (l ^ (j & 63));
        f32x2 w;
        w.x = w_fc2[l * HID + j];
        w.y = w_fc2[(l + 64) * HID + j];
        ld_fc2[pos] = w;
    }

    const int lane  = tid & 63;
    const int gwave = blockIdx.x * (BLOCK_S / 64) + (tid >> 6);

    // small weights -> registers
    f32x2 w1[SDIM];
    #pragma unroll
    for (int k = 0; k < SDIM; ++k) {
        w1[k].x = w_fc1[lane * SDIM + k];
        w1[k].y = w_fc1[(lane + 64) * SDIM + k];
    }
    const float wm_a = w_mean[lane], wm_b = w_mean[lane + 64];
    const float ws_a = w_std [lane], ws_b = w_std [lane + 64];

    const float a1 = fminf(fmaxf(p_alpha1[0], 0.f), 1.f);
    const float b1 = fminf(fmaxf(p_beta1 [0], 0.f), 1.f);
    const float a2 = fminf(fmaxf(p_alpha2[0], 0.f), 1.f);
    const float b2 = fminf(fmaxf(p_beta2 [0], 0.f), 1.f);
    const float t1 = p_thr1[0];
    const float t2 = p_thr2[0];
    const f32x2 a1v = {a1, a1}, b1v = {b1, b1}, a2v = {a2, a2}, b2v = {b2, b2};

    const float* __restrict__ rec2_a = w_rec2 + lane * HID;
    const float* __restrict__ rec2_b = w_rec2 + (lane + 64) * HID;

    __syncthreads();

    // fused walk over one spike-mask half: fc2 (this step, LDS) into f,
    // rec1 (next step, global/L2) into r. Hand-rotated.
    auto walk = [&](unsigned long long m,
                    const f32x2* __restrict__ ldsb,   // fc2 base for this half
                    const f32x2* __restrict__ gb,     // R base for this half
                    f32x2& f, f32x2& r) {
        if (!m) return;
        int j = __builtin_ctzll(m); m &= m - 1;
        f32x2 wf = ldsb[(j << 6) | (lane ^ j)];
        f32x2 wr = gb[(j << 6) | lane];
        while (m) {
            const int j2 = __builtin_ctzll(m); m &= m - 1;
            const f32x2 wf2 = ldsb[(j2 << 6) | (lane ^ j2)];
            const f32x2 wr2 = gb[(j2 << 6) | lane];
            f += wf; r += wr;
            wf = wf2; wr = wr2;
        }
        f += wf; r += wr;
    };
    auto walkg = [&](unsigned long long m, int jbase, f32x2& f) {
        while (m) {
            const int j = __builtin_ctzll(m) + jbase; m &= m - 1;
            f.x += rec2_a[j];
            f.y += rec2_b[j];
        }
    };

    const f32x2* __restrict__ fc2Lo = ld_fc2;
    const f32x2* __restrict__ fc2Hi = ld_fc2 + (64 << 6);
    const f32x2* __restrict__ RLo   = R;
    const f32x2* __restrict__ RHi   = R + (64 << 6);

    for (int e = 0; e < EPW_S; ++e) {
        const int b = gwave + WAVES_S * e;

        // cur1_in = state[b] @ w_fc1.T  (wave-uniform scalar loads)
        f32x2 cur = {0.f, 0.f};
        #pragma unroll
        for (int k = 0; k < SDIM; ++k) {
            const float s = state[b * SDIM + k];
            const f32x2 sv = {s, s};
            cur = __builtin_elementwise_fma(sv, w1[k], cur);
        }

        f32x2 s1 = {0.f, 0.f}, m1 = {0.f, 0.f};
        f32x2 s2 = {0.f, 0.f}, m2 = {0.f, 0.f};
        bool k1a = false, k1b = false, k2a = false, k2b = false;
        f32x2 cnt = {0.f, 0.f};
        unsigned long long M2a = 0ull, M2b = 0ull;
        f32x2 r = {0.f, 0.f};   // rec1 contribution computed in previous step

        #pragma unroll 1
        for (int t = 0; t < NSTEP; ++t) {
            // ----- layer 1 -----
            s1 = __builtin_elementwise_fma(a1v, s1, cur + r);
            const f32x2 rst1 = {k1a ? t1 : 0.f, k1b ? t1 : 0.f};
            m1 = __builtin_elementwise_fma(b1v, m1, s1) - rst1;
            k1a = (m1.x - t1) > 0.f;
            k1b = (m1.y - t1) > 0.f;
            const unsigned long long M1a = __ballot(k1a);
            const unsigned long long M1b = __ballot(k1b);

            // ----- fused gathers: fc2 (this step) + rec1 (next step) -----
            f32x2 f = {0.f, 0.f};
            r = (f32x2){0.f, 0.f};
            walk(M1a, fc2Lo, RLo, f, r);
            walk(M1b, fc2Hi, RHi, f, r);

            // rare layer-2 recurrence
            if ((M2a | M2b) != 0ull) {
                walkg(M2a, 0,  f);
                walkg(M2b, 64, f);
            }

            // ----- layer 2 -----
            s2 = __builtin_elementwise_fma(a2v, s2, f);
            const f32x2 rst2 = {k2a ? t2 : 0.f, k2b ? t2 : 0.f};
            m2 = __builtin_elementwise_fma(b2v, m2, s2) - rst2;
            k2a = (m2.x - t2) > 0.f;
            k2b = (m2.y - t2) > 0.f;
            M2a = __ballot(k2a);
            M2b = __ballot(k2b);
            const f32x2 one = {k2a ? 1.f : 0.f, k2b ? 1.f : 0.f};
            cnt += one;
        }

        // ----- head -----
        const float av_a = cnt.x * (1.f / (float)NSTEP);
        const float av_b = cnt.y * (1.f / (float)NSTEP);
        float dm = av_a * wm_a + av_b * wm_b;
        float ds = av_a * ws_a + av_b * ws_b;
        #pragma unroll
        for (int off = 32; off > 0; off >>= 1) {
            dm += __shfl_xor(dm, off, 64);
            ds += __shfl_xor(ds, off, 64);
        }
        if (lane == 0) {
            out[b] = tanhf(dm);
            const float sg = 1.f / (1.f + expf(-(ds + 2.f)));
            out[BATCH + b] = 1.9f * sg + 0.1f;
        }
    }
}

// ---------------- fallback: v4 LDS kernel (workspace too small) ------------
constexpr int BLOCK_L = 1024;
constexpr int GRID_L  = 256;
constexpr int WAVES_L = GRID_L * (BLOCK_L / 64);
constexpr int EPW_L   = BATCH / WAVES_L;
constexpr int PAIRS_L = EPW_L / 2;

__global__ __launch_bounds__(BLOCK_L) void snn_fwd_lds(
    const float* __restrict__ state,
    const float* __restrict__ w_fc1,
    const float* __restrict__ w_rec1,
    const float* __restrict__ w_fc2,
    const float* __restrict__ w_rec2,
    const float* __restrict__ w_mean,
    const float* __restrict__ w_std,
    const float* __restrict__ p_alpha1, const float* __restrict__ p_beta1,
    const float* __restrict__ p_thr1,
    const float* __restrict__ p_alpha2, const float* __restrict__ p_beta2,
    const float* __restrict__ p_thr2,
    float* __restrict__ out)
{
    __shared__ f32x4 ldw[HID * 64];   // 128 KiB
    const int tid = threadIdx.x;

    for (int v = tid; v < HID * 64; v += BLOCK_L) {
        const int l = v >> 7;
        const int j = v & 127;
        const int pos = (j << 6) | (l ^ (j & 63));
        f32x4 w;
        w.x = w_rec1[l * HID + j];
        w.y = w_rec1[(l + 64) * HID + j];
        w.z = w_fc2 [l * HID + j];
        w.w = w_fc2 [(l + 64) * HID + j];
        ldw[pos] = w;
    }

    const int lane  = tid & 63;
    const int gwave = blockIdx.x * (BLOCK_L / 64) + (tid >> 6);

    f32x2 w1[SDIM];
    #pragma unroll
    for (int k = 0; k < SDIM; ++k) {
        w1[k].x = w_fc1[lane * SDIM + k];
        w1[k].y = w_fc1[(lane + 64) * SDIM + k];
    }
    const float wm_a = w_mean[lane], wm_b = w_mean[lane + 64];
    const float ws_a = w_std [lane], ws_b = w_std [lane + 64];

    const float a1 = fminf(fmaxf(p_alpha1[0], 0.f), 1.f);
    const float b1 = fminf(fmaxf(p_beta1 [0], 0.f), 1.f);
    const float a2 = fminf(fmaxf(p_alpha2[0], 0.f), 1.f);
    const float b2 = fminf(fmaxf(p_beta2 [0], 0.f), 1.f);
    const float t1 = p_thr1[0];
    const float t2 = p_thr2[0];
    const f32x2 a1v = {a1, a1}, b1v = {b1, b1}, a2v = {a2, a2}, b2v = {b2, b2};

    const float* __restrict__ rec2_a = w_rec2 + lane * HID;
    const float* __restrict__ rec2_b = w_rec2 + (lane + 64) * HID;

    __syncthreads();

    auto walk2 = [&](unsigned long long m, const f32x4* __restrict__ base,
                     f32x2& f, f32x2& r) {
        if (!m) return;
        int j = __builtin_ctzll(m); m &= m - 1;
        f32x4 w = base[(j << 6) | (lane ^ j)];
        while (m) {
            const int j2 = __builtin_ctzll(m); m &= m - 1;
            const f32x4 w2 = base[(j2 << 6) | (lane ^ j2)];
            r += __builtin_shufflevector(w, w, 0, 1);
            f += __builtin_shufflevector(w, w, 2, 3);
            w = w2;
        }
        r += __builtin_shufflevector(w, w, 0, 1);
        f += __builtin_shufflevector(w, w, 2, 3);
    };
    auto walkg = [&](unsigned long long m, int jbase, f32x2& f) {
        while (m) {
            const int j = __builtin_ctzll(m) + jbase; m &= m - 1;
            f.x += rec2_a[j];
            f.y += rec2_b[j];
        }
    };

    const f32x4* __restrict__ baseLo = ldw;
    const f32x4* __restrict__ baseHi = ldw + (64 << 6);

    float sx[SDIM], sy[SDIM];
    #pragma unroll
    for (int k = 0; k < SDIM; ++k) {
        sx[k] = state[(gwave) * SDIM + k];
        sy[k] = state[(gwave + WAVES_L) * SDIM + k];
    }

    for (int e = 0; e < PAIRS_L; ++e) {
        const int bx = gwave + WAVES_L * (2 * e);
        const int by = gwave + WAVES_L * (2 * e + 1);

        f32x2 curx = {0.f, 0.f}, cury = {0.f, 0.f};
        #pragma unroll
        for (int k = 0; k < SDIM; ++k) {
            const f32x2 sxv = {sx[k], sx[k]};
            const f32x2 syv = {sy[k], sy[k]};
            curx = __builtin_elementwise_fma(sxv, w1[k], curx);
            cury = __builtin_elementwise_fma(syv, w1[k], cury);
        }

        float sxn[SDIM], syn2p[SDIM];
        if (e + 1 < PAIRS_L) {
            const int bxn = gwave + WAVES_L * (2 * e + 2);
            const int byn = gwave + WAVES_L * (2 * e + 3);
            #pragma unroll
            for (int k = 0; k < SDIM; ++k) {
                sxn[k]   = state[bxn * SDIM + k];
                syn2p[k] = state[byn * SDIM + k];
            }
        }

        f32x2 s1x = {0.f, 0.f}, m1x = {0.f, 0.f}, s2x = {0.f, 0.f}, m2x = {0.f, 0.f};
        f32x2 s1y = {0.f, 0.f}, m1y = {0.f, 0.f}, s2y = {0.f, 0.f}, m2y = {0.f, 0.f};
        bool k1xa = false, k1xb = false, k2xa = false, k2xb = false;
        bool k1ya = false, k1yb = false, k2ya = false, k2yb = false;
        f32x2 cx = {0.f, 0.f}, cy = {0.f, 0.f};
        unsigned long long M2xa = 0ull, M2xb = 0ull, M2ya = 0ull, M2yb = 0ull;
        f32x2 rx = {0.f, 0.f}, ry = {0.f, 0.f};

        #pragma unroll 1
        for (int t = 0; t < NSTEP; ++t) {
            s1x = __builtin_elementwise_fma(a1v, s1x, curx + rx);
            s1y = __builtin_elementwise_fma(a1v, s1y, cury + ry);
            const f32x2 rst1x = {k1xa ? t1 : 0.f, k1xb ? t1 : 0.f};
            const f32x2 rst1y = {k1ya ? t1 : 0.f, k1yb ? t1 : 0.f};
            m1x = __builtin_elementwise_fma(b1v, m1x, s1x) - rst1x;
            m1y = __builtin_elementwise_fma(b1v, m1y, s1y) - rst1y;
            k1xa = (m1x.x - t1) > 0.f;
            k1xb = (m1x.y - t1) > 0.f;
            k1ya = (m1y.x - t1) > 0.f;
            k1yb = (m1y.y - t1) > 0.f;
            const unsigned long long M1xa = __ballot(k1xa);
            const unsigned long long M1xb = __ballot(k1xb);
            const unsigned long long M1ya = __ballot(k1ya);
            const unsigned long long M1yb = __ballot(k1yb);

            f32x2 fx = {0.f, 0.f}, fy = {0.f, 0.f};
            rx = (f32x2){0.f, 0.f}; ry = (f32x2){0.f, 0.f};
            walk2(M1xa, baseLo, fx, rx);
            walk2(M1ya, baseLo, fy, ry);
            walk2(M1xb, baseHi, fx, rx);
            walk2(M1yb, baseHi, fy, ry);

            if ((M2xa | M2xb | M2ya | M2yb) != 0ull) {
                walkg(M2xa, 0,  fx);
                walkg(M2xb, 64, fx);
                walkg(M2ya, 0,  fy);
                walkg(M2yb, 64, fy);
            }

            s2x = __builtin_elementwise_fma(a2v, s2x, fx);
            s2y = __builtin_elementwise_fma(a2v, s2y, fy);
            const f32x2 rst2x = {k2xa ? t2 : 0.f, k2xb ? t2 : 0.f};
            const f32x2 rst2y = {k2ya ? t2 : 0.f, k2yb ? t2 : 0.f};
            m2x = __builtin_elementwise_fma(b2v, m2x, s2x) - rst2x;
            m2y = __builtin_elementwise_fma(b2v, m2y, s2y) - rst2y;
            k2xa = (m2x.x - t2) > 0.f;
            k2xb = (m2x.y - t2) > 0.f;
            k2ya = (m2y.x - t2) > 0.f;
            k2yb = (m2y.y - t2) > 0.f;
            M2xa = __ballot(k2xa);
            M2xb = __ballot(k2xb);
            M2ya = __ballot(k2ya);
            M2yb = __ballot(k2yb);
            const f32x2 onex = {k2xa ? 1.f : 0.f, k2xb ? 1.f : 0.f};
            const f32x2 oney = {k2ya ? 1.f : 0.f, k2yb ? 1.f : 0.f};
            cx += onex;
            cy += oney;
        }

        const float axa = cx.x * (1.f / (float)NSTEP);
        const float axb = cx.y * (1.f / (float)NSTEP);
        const float aya = cy.x * (1.f / (float)NSTEP);
        const float ayb = cy.y * (1.f / (float)NSTEP);
        float dmx = axa * wm_a + axb * wm_b;
        float dsx = axa * ws_a + axb * ws_b;
        float dmy = aya * wm_a + ayb * wm_b;
        float dsy = aya * ws_a + ayb * ws_b;
        #pragma unroll
        for (int off = 32; off > 0; off >>= 1) {
            dmx += __shfl_xor(dmx, off, 64);
            dsx += __shfl_xor(dsx, off, 64);
            dmy += __shfl_xor(dmy, off, 64);
            dsy += __shfl_xor(dsy, off, 64);
        }
        if (lane == 0) {
            out[bx] = tanhf(dmx);
            out[by] = tanhf(dmy);
            const float sgx = 1.f / (1.f + expf(-(dsx + 2.f)));
            const float sgy = 1.f / (1.f + expf(-(dsy + 2.f)));
            out[BATCH + bx] = 1.9f * sgx + 0.1f;
            out[BATCH + by] = 1.9f * sgy + 0.1f;
        }

        if (e + 1 < PAIRS_L) {
            #pragma unroll
            for (int k = 0; k < SDIM; ++k) { sx[k] = sxn[k]; sy[k] = syn2p[k]; }
        }
    }
}

extern "C" void kernel_launch(void* const* d_in, const int* in_sizes, int n_in,
                              void* d_out, int out_size, void* d_ws, size_t ws_size,
                              hipStream_t stream) {
    (void)in_sizes; (void)n_in; (void)out_size;
    if (d_ws != nullptr && ws_size >= (size_t)(HID * 64 * sizeof(f32x2))) {
        f32x2* R = (f32x2*)d_ws;
        pack_rec1<<<32, 256, 0, stream>>>((const float*)d_in[2], R);
        snn_fwd_split<<<GRID_S, BLOCK_S, 0, stream>>>(
            (const float*)d_in[0],  // state
            (const float*)d_in[1],  // w_fc1
            R,                      // packed rec1
            (const float*)d_in[3],  // w_fc2
            (const float*)d_in[4],  // w_rec2
            (const float*)d_in[5],  // w_mean
            (const float*)d_in[6],  // w_std
            (const float*)d_in[7], (const float*)d_in[8], (const float*)d_in[9],
            (const float*)d_in[10], (const float*)d_in[11], (const float*)d_in[12],
            (float*)d_out);
    } else {
        snn_fwd_lds<<<GRID_L, BLOCK_L, 0, stream>>>(
            (const float*)d_in[0], (const float*)d_in[1], (const float*)d_in[2],
            (const float*)d_in[3], (const float*)d_in[4], (const float*)d_in[5],
            (const float*)d_in[6],
            (const float*)d_in[7], (const float*)d_in[8], (const float*)d_in[9],
            (const float*)d_in[10], (const float*)d_in[11], (const float*)d_in[12],
            (float*)d_out);
    }
}